// Round 8
// baseline (171.643 us; speedup 1.0000x reference)
//
#include <hip/hip_runtime.h>
#include <hip/hip_bf16.h>

// RBF-KAN as one fused bf16 MFMA GEMM:
//   out[b,o] = sum_k A[b,k] * W[k,o] + bias[o]
//   k = ic*832 + slot*64 + ii, i = ic*64+ii
//   slot==0: A = x[b,i];  slot>=1: A = basis(x[b,i], g=slot-1)
// basis recurrence with u = x*1.375 + 5.5:
//   bb_0 = exp(-u^2/2); bb_{g+1} = bb_g*ff_g; ff_0 = exp(u-0.5); ff_{g+1} = ff_g*e^-1
//
// Round 8: r3's verified geometry (block 128x256, 512 thr, 8 waves 2x4,
// wave 64x64, k-granule conflict-free LDS) + proper T3+T4 schedule:
// 2 phases/K-step, each {emit-A half | stage-half(t+2) | 8 ds_read ->
// barrier -> lgkmcnt(0)+sched_barrier -> setprio(1) 8 MFMA setprio(0) ->
// barrier}; B in a 3-deep ring; ONE counted vmcnt(4) per step (phase 1) so
// t+2's loads stay in flight across barriers (never vmcnt(0) mid-loop).

#define N_DIM 512
#define I_DIM 512
#define KTOT  6656
#define NSTEP 104      // 104 K-steps of 64 = 8 chunks x 13 slots

typedef short short8 __attribute__((ext_vector_type(8)));
typedef float f32x16 __attribute__((ext_vector_type(16)));
typedef unsigned int u32x4 __attribute__((ext_vector_type(4)));

#define CVTPK(dst, lo, hi) \
  asm("v_cvt_pk_bf16_f32 %0, %1, %2" : "=v"(dst) : "v"(lo), "v"(hi))

__device__ __forceinline__ unsigned short f2bf(float f) {
  union { float f; unsigned int u; } c; c.f = f;
  unsigned int r = (c.u + 0x7FFFu + ((c.u >> 16) & 1)) >> 16;  // RNE, finite only
  return (unsigned short)r;
}

// ---------------- prep: repack coeff + base_w into bf16 Wb2[g][o][e] ----------------
// g = k >> 3 (16B k-granule, 0..831), e = k & 7.
__global__ __launch_bounds__(256) void prep_w(const float* __restrict__ coeff,
                                              const float* __restrict__ base_w,
                                              unsigned short* __restrict__ Wb2) {
  int t = blockIdx.x * 256 + threadIdx.x;   // 851968 threads, 4 shorts each
  int e0 = (t & 1) * 4;
  int go = t >> 1;                          // g*512 + o
  int o  = go & 511;
  int g  = go >> 9;
  int k4 = g * 8 + e0;
  int ic = k4 / 832;
  int rem = k4 - ic * 832;
  int slot = rem >> 6;
  int ii = rem & 63;
  int i = ic * 64 + ii;
  float v0, v1, v2, v3;
  if (slot == 0) {
    const float4 bw = *(const float4*)(base_w + (size_t)o * I_DIM + i);
    v0 = bw.x; v1 = bw.y; v2 = bw.z; v3 = bw.w;
  } else {
    int gg = slot - 1;
    const float* cp = coeff + (size_t)i * (N_DIM * 12) + o * 12 + gg;
    v0 = cp[0]; v1 = cp[6144]; v2 = cp[2 * 6144]; v3 = cp[3 * 6144];
  }
  ushort4 s;
  s.x = f2bf(v0); s.y = f2bf(v1); s.z = f2bf(v2); s.w = f2bf(v3);
  *(ushort4*)(Wb2 + (size_t)go * 8 + e0) = s;
}

// ---------------- main fused GEMM ----------------
__global__ __launch_bounds__(512, 2) void kan_gemm(const float* __restrict__ x,
                                                   const unsigned short* __restrict__ Wb2,
                                                   const float* __restrict__ bias,
                                                   float* __restrict__ out) {
  // k-granule blocked: A [2][kg 8][row 128][8 bf16] (16KB ea),
  //                    B ring [3][kg 8][col 256][8 bf16] (32KB ea) -> 128KB
  __shared__ unsigned short Asw[2][8 * 128 * 8];
  __shared__ unsigned short Bsw[3][8 * 256 * 8];

  const int tid  = threadIdx.x;
  const int lane = tid & 63;
  const int wid  = tid >> 6;                  // 8 waves: 2(wm) x 4(wn)
  const int wm   = wid >> 2, wn = wid & 3;    // wave tile 64x64
  const int l31  = lane & 31, hl = lane >> 5;

  const int rb = blockIdx.x >> 1;             // 128 row-blocks
  const int cb = blockIdx.x & 1;              // 2 col-blocks
  const int M0 = rb * 128;
  const int N0 = cb * 256;

  // ---- A staging map: thread -> (row arow, k-quarter kgp), 16 elems ----
  const int arow = tid & 127;
  const int kgp  = tid >> 7;                  // 0..3 -> granules 2kgp, 2kgp+1
  const float* xg = x + (size_t)(M0 + arow) * I_DIM + kgp * 16;
  int aoff[2];
#pragma unroll
  for (int h = 0; h < 2; ++h) aoff[h] = ((kgp * 2 + h) * 128 + arow) * 16;  // bytes

  // ---- B staging: wave w stages granule w, cols q*64..q*64+63 (1KB each) ----
  const unsigned short* bsrc[4];
  int bdst[4];                                // byte offsets within ring slot
#pragma unroll
  for (int q = 0; q < 4; ++q) {
    bsrc[q] = Wb2 + ((size_t)wid * 512 + N0 + q * 64 + lane) * 8;  // + t*32768
    bdst[q] = (wid * 256 + q * 64) * 16;
  }

#define STAGE2(T_, RING_, H_) do {                                             \
    const size_t ko_ = (size_t)(T_) * 32768;                                   \
    char* d_ = (char*)&Bsw[RING_][0];                                          \
    _Pragma("unroll")                                                          \
    for (int q_ = 2 * (H_); q_ < 2 * (H_) + 2; ++q_)                           \
      __builtin_amdgcn_global_load_lds(                                        \
          (const __attribute__((address_space(1))) void*)(bsrc[q_] + ko_),     \
          (__attribute__((address_space(3))) void*)(d_ + bdst[q_]), 16, 0, 0); \
  } while (0)

  // ---- compute-side byte bases ----
  const int aBase = (hl * 128 + wm * 64 + l31) * 16;   // + s*4096 (+512 fb=1)
  const int bBase = (hl * 256 + wn * 64 + l31) * 16;   // + s*8192 (+512 fo=1)

  f32x16 acc[2][2];
#pragma unroll
  for (int i = 0; i < 2; ++i)
#pragma unroll
    for (int j = 0; j < 2; ++j)
#pragma unroll
      for (int r = 0; r < 16; ++r) acc[i][j][r] = 0.f;

  // ---- A-gen state: 16 i-values/thread; half h2 handles j in [8h2, 8h2+8) ----
  float bb[16], ff[16];

  auto emit_half = [&](char* pA, bool s0, int eic, int h2) {
    unsigned int w[4];
    const int j0 = h2 * 8;
    if (s0) {
      const float* xp = xg + (size_t)eic * 64 + h2 * 8;
      float4 p = *(const float4*)(xp);
      float4 q = *(const float4*)(xp + 4);
      float f[8] = {p.x, p.y, p.z, p.w, q.x, q.y, q.z, q.w};
#pragma unroll
      for (int j2 = 0; j2 < 4; ++j2) CVTPK(w[j2], f[2 * j2], f[2 * j2 + 1]);
      *(u32x4*)(pA + aoff[h2]) = (u32x4){w[0], w[1], w[2], w[3]};
#pragma unroll
      for (int e = 0; e < 8; ++e) {
        float u = fmaf(f[e], 1.375f, 5.5f);
        bb[j0 + e] = exp2f(-0.72134752044448170f * u * u);                         // exp(-u^2/2)
        ff[j0 + e] = exp2f(fmaf(u, 1.44269504088896340f, -0.72134752044448170f)); // exp(u-1/2)
      }
    } else {
#pragma unroll
      for (int j2 = 0; j2 < 4; ++j2) CVTPK(w[j2], bb[j0 + 2 * j2], bb[j0 + 2 * j2 + 1]);
      *(u32x4*)(pA + aoff[h2]) = (u32x4){w[0], w[1], w[2], w[3]};
#pragma unroll
      for (int e = 0; e < 8; ++e) {
        bb[j0 + e] *= ff[j0 + e];
        ff[j0 + e] *= 0.36787944117144233f;   // e^-1
      }
    }
  };

#define MFMA_QUAD(AV0, AV1, BV0, BV1)                                              \
  acc[0][0] = __builtin_amdgcn_mfma_f32_32x32x16_bf16(AV0, BV0, acc[0][0], 0, 0, 0); \
  acc[0][1] = __builtin_amdgcn_mfma_f32_32x32x16_bf16(AV0, BV1, acc[0][1], 0, 0, 0); \
  acc[1][0] = __builtin_amdgcn_mfma_f32_32x32x16_bf16(AV1, BV0, acc[1][0], 0, 0, 0); \
  acc[1][1] = __builtin_amdgcn_mfma_f32_32x32x16_bf16(AV1, BV1, acc[1][1], 0, 0, 0)

  // ================= prologue =================
  // emit A for step 0 (e=0: slot 0, chunk 0) into Asw[0]; stage B[0],B[1]
  emit_half((char*)&Asw[0][0], true, 0, 0);
  emit_half((char*)&Asw[0][0], true, 0, 1);
  STAGE2(0, 0, 0); STAGE2(0, 0, 1);
  STAGE2(1, 1, 0); STAGE2(1, 1, 1);
  asm volatile("s_waitcnt vmcnt(4) lgkmcnt(0)" ::: "memory");  // B[0]+A-writes done
  __builtin_amdgcn_s_barrier();

  // ================= main loop =================
  int cur3 = 0;          // B ring index of step t
  int eslot = 1, eic = 0;  // slot/chunk of e = t+1 (emit target)
#pragma unroll 1
  for (int t = 0; t < NSTEP; ++t) {
    const int abuf = t & 1;
    const char* pA = (const char*)&Asw[abuf][0];
    const char* pB = (const char*)&Bsw[cur3][0];
    char* pAe = (char*)&Asw[abuf ^ 1][0];
    const bool doEmit  = (t < NSTEP - 1);
    const bool doStage = (t < NSTEP - 2);
    const bool s0 = (eslot == 0);
    int nring = cur3 + 2; if (nring >= 3) nring -= 3;

    // ---------------- phase 0: s = 0,1 ----------------
    {
      if (doEmit)  emit_half(pAe, s0, eic, 0);
      if (doStage) STAGE2(t + 2, nring, 0);
      short8 a00 = *(const short8*)(pA + aBase);
      short8 a01 = *(const short8*)(pA + aBase + 512);
      short8 b00 = *(const short8*)(pB + bBase);
      short8 b01 = *(const short8*)(pB + bBase + 512);
      short8 a10 = *(const short8*)(pA + aBase + 4096);
      short8 a11 = *(const short8*)(pA + aBase + 4096 + 512);
      short8 b10 = *(const short8*)(pB + bBase + 8192);
      short8 b11 = *(const short8*)(pB + bBase + 8192 + 512);
      __builtin_amdgcn_s_barrier();
      asm volatile("s_waitcnt lgkmcnt(0)" ::: "memory");
      __builtin_amdgcn_sched_barrier(0);
      __builtin_amdgcn_s_setprio(1);
      MFMA_QUAD(a00, a01, b00, b01);
      MFMA_QUAD(a10, a11, b10, b11);
      __builtin_amdgcn_s_setprio(0);
      __builtin_amdgcn_sched_barrier(0);
      __builtin_amdgcn_s_barrier();
    }

    // ---------------- phase 1: s = 2,3 ----------------
    {
      if (doEmit)  emit_half(pAe, s0, eic, 1);
      if (doStage) STAGE2(t + 2, nring, 1);
      short8 a00 = *(const short8*)(pA + aBase + 2 * 4096);
      short8 a01 = *(const short8*)(pA + aBase + 2 * 4096 + 512);
      short8 b00 = *(const short8*)(pB + bBase + 2 * 8192);
      short8 b01 = *(const short8*)(pB + bBase + 2 * 8192 + 512);
      short8 a10 = *(const short8*)(pA + aBase + 3 * 4096);
      short8 a11 = *(const short8*)(pA + aBase + 3 * 4096 + 512);
      short8 b10 = *(const short8*)(pB + bBase + 3 * 8192);
      short8 b11 = *(const short8*)(pB + bBase + 3 * 8192 + 512);
      // counted fence: drain t+1's 4 loads (oldest); keep t+2's 4 in flight
      if (doStage) { asm volatile("s_waitcnt vmcnt(4)" ::: "memory"); }
      else         { asm volatile("s_waitcnt vmcnt(0)" ::: "memory"); }
      __builtin_amdgcn_s_barrier();
      asm volatile("s_waitcnt lgkmcnt(0)" ::: "memory");
      __builtin_amdgcn_sched_barrier(0);
      __builtin_amdgcn_s_setprio(1);
      MFMA_QUAD(a00, a01, b00, b01);
      MFMA_QUAD(a10, a11, b10, b11);
      __builtin_amdgcn_s_setprio(0);
      __builtin_amdgcn_sched_barrier(0);
      __builtin_amdgcn_s_barrier();
    }

    // advance counters
    if (++eslot == 13) { eslot = 0; ++eic; }
    cur3 = (cur3 == 2) ? 0 : cur3 + 1;
  }

  // ---- epilogue: D col(o) = lane&31, row(b) = (r&3)+8*(r>>2)+4*hl ----
  float bv[2];
#pragma unroll
  for (int fo = 0; fo < 2; ++fo) bv[fo] = bias[N0 + wn * 64 + fo * 32 + l31];
  const int rbase = 4 * hl;
#pragma unroll
  for (int fb = 0; fb < 2; ++fb) {
#pragma unroll
    for (int fo = 0; fo < 2; ++fo) {
      const size_t cix = (size_t)(N0 + wn * 64 + fo * 32 + l31);
#pragma unroll
      for (int r = 0; r < 16; ++r) {
        int row = M0 + wm * 64 + fb * 32 + (r & 3) + 8 * (r >> 2) + rbase;
        out[(size_t)row * N_DIM + cix] = acc[fb][fo][r] + bv[fo];
      }
    }
  }
}

extern "C" void kernel_launch(void* const* d_in, const int* in_sizes, int n_in,
                              void* d_out, int out_size, void* d_ws, size_t ws_size,
                              hipStream_t stream) {
  const float* x      = (const float*)d_in[0];
  const float* coeff  = (const float*)d_in[1];
  const float* base_w = (const float*)d_in[2];
  const float* base_b = (const float*)d_in[3];
  // d_in[4] (centers) is implied by u = x*1.375 + 5.5 (exact)
  unsigned short* Wb2 = (unsigned short*)d_ws;   // needs 6,815,744 B

  prep_w<<<3328, 256, 0, stream>>>(coeff, base_w, Wb2);
  kan_gemm<<<256, 512, 0, stream>>>(x, Wb2, base_b, (float*)d_out);
}

// Round 9
// 157.180 us; speedup vs baseline: 1.0920x; 1.0920x over previous
//
#include <hip/hip_runtime.h>
#include <hip/hip_bf16.h>

// RBF-KAN as one fused bf16 MFMA GEMM:
//   out[b,o] = sum_k A[b,k] * W[k,o] + bias[o]
//   k = ic*832 + slot*64 + ii, i = ic*64+ii
//   slot==0: A = x[b,i];  slot>=1: A = basis(x[b,i], g=slot-1)
// basis recurrence with u = x*1.375 + 5.5:
//   bb_0 = exp(-u^2/2); bb_{g+1} = bb_g*ff_g; ff_0 = exp(u-0.5); ff_{g+1} = ff_g*e^-1
//
// Round 9: r3 geometry (128x256 block, 512 thr, 8 waves 2x4, wave 64x64,
// k-granule conflict-free LDS) with a single-barrier counted-vmcnt step:
//   {16 ds_read | stage(t+2) | emit A(t+1): cvtpk+2 ds_write | 16 MFMA |
//    shadow: state advance + x-preload | s_waitcnt vmcnt(4|8) lgkmcnt(0) |
//    s_barrier}
// - ONE barrier/step; never vmcnt(0) mid-loop (stage loads span a full step).
// - A-gen VALU (recurrence / exp2 init) AFTER the MFMA cluster (drain shadow).
// - x chunks preloaded into registers 10+ steps before use so no implicit
//   vmcnt(0) from consuming a young load.
// WAR ledger: reads complete before each wave's MFMA (lgkm) => before barrier;
// all cross-step writes (emit t+2 into read-buf, stage t+3 into read-ring)
// are issued after that barrier. A(t+1) writes drained by lgkmcnt(0) at fence;
// B(t+1) stages drained by the counted vmcnt.

#define N_DIM 512
#define I_DIM 512
#define KTOT  6656
#define NSTEP 104      // 104 K-steps of 64 = 8 chunks x 13 slots

typedef short short8 __attribute__((ext_vector_type(8)));
typedef float f32x16 __attribute__((ext_vector_type(16)));
typedef unsigned int u32x4 __attribute__((ext_vector_type(4)));

#define CVTPK(dst, lo, hi) \
  asm("v_cvt_pk_bf16_f32 %0, %1, %2" : "=v"(dst) : "v"(lo), "v"(hi))

__device__ __forceinline__ unsigned short f2bf(float f) {
  union { float f; unsigned int u; } c; c.f = f;
  unsigned int r = (c.u + 0x7FFFu + ((c.u >> 16) & 1)) >> 16;  // RNE, finite only
  return (unsigned short)r;
}

// ---------------- prep: repack coeff + base_w into bf16 Wb2[g][o][e] ----------------
// g = k >> 3 (16B k-granule, 0..831), e = k & 7.
__global__ __launch_bounds__(256) void prep_w(const float* __restrict__ coeff,
                                              const float* __restrict__ base_w,
                                              unsigned short* __restrict__ Wb2) {
  int t = blockIdx.x * 256 + threadIdx.x;   // 851968 threads, 4 shorts each
  int e0 = (t & 1) * 4;
  int go = t >> 1;                          // g*512 + o
  int o  = go & 511;
  int g  = go >> 9;
  int k4 = g * 8 + e0;
  int ic = k4 / 832;
  int rem = k4 - ic * 832;
  int slot = rem >> 6;
  int ii = rem & 63;
  int i = ic * 64 + ii;
  float v0, v1, v2, v3;
  if (slot == 0) {
    const float4 bw = *(const float4*)(base_w + (size_t)o * I_DIM + i);
    v0 = bw.x; v1 = bw.y; v2 = bw.z; v3 = bw.w;
  } else {
    int gg = slot - 1;
    const float* cp = coeff + (size_t)i * (N_DIM * 12) + o * 12 + gg;
    v0 = cp[0]; v1 = cp[6144]; v2 = cp[2 * 6144]; v3 = cp[3 * 6144];
  }
  ushort4 s;
  s.x = f2bf(v0); s.y = f2bf(v1); s.z = f2bf(v2); s.w = f2bf(v3);
  *(ushort4*)(Wb2 + (size_t)go * 8 + e0) = s;
}

// ---------------- main fused GEMM ----------------
__global__ __launch_bounds__(512, 2) void kan_gemm(const float* __restrict__ x,
                                                   const unsigned short* __restrict__ Wb2,
                                                   const float* __restrict__ bias,
                                                   float* __restrict__ out) {
  // A dbuf 2x16KB, B ring 3x32KB -> 128KB
  __shared__ unsigned short Asw[2][8 * 128 * 8];
  __shared__ unsigned short Bsw[3][8 * 256 * 8];

  const int tid  = threadIdx.x;
  const int lane = tid & 63;
  const int wid  = tid >> 6;                  // 8 waves: 2(wm) x 4(wn)
  const int wm   = wid >> 2, wn = wid & 3;    // wave tile 64x64
  const int l31  = lane & 31, hl = lane >> 5;

  const int rb = blockIdx.x >> 1;             // 128 row-blocks
  const int cb = blockIdx.x & 1;              // 2 col-blocks
  const int M0 = rb * 128;
  const int N0 = cb * 256;

  // ---- A staging map: thread -> (row arow, k-eighth kgp), 16 elems ----
  const int arow = tid & 127;
  const int kgp  = tid >> 7;                  // granules 2kgp, 2kgp+1
  const float* xg = x + (size_t)(M0 + arow) * I_DIM + kgp * 16;
  const int aoff0 = ((kgp * 2) * 128 + arow) * 16;      // bytes
  const int aoff1 = ((kgp * 2 + 1) * 128 + arow) * 16;

  // ---- B staging: wave w stages granule w, 4 x 1KB per step ----
  const unsigned short* bsrc[4];
  int bdst[4];
#pragma unroll
  for (int q = 0; q < 4; ++q) {
    bsrc[q] = Wb2 + ((size_t)wid * 512 + N0 + q * 64 + lane) * 8;  // + t*32768
    bdst[q] = (wid * 256 + q * 64) * 16;
  }

#define STAGE(T_, RING_) do {                                                  \
    const size_t ko_ = (size_t)(T_) * 32768;                                   \
    char* d_ = (char*)&Bsw[RING_][0];                                          \
    _Pragma("unroll")                                                          \
    for (int q_ = 0; q_ < 4; ++q_)                                             \
      __builtin_amdgcn_global_load_lds(                                        \
          (const __attribute__((address_space(1))) void*)(bsrc[q_] + ko_),     \
          (__attribute__((address_space(3))) void*)(d_ + bdst[q_]), 16, 0, 0); \
  } while (0)

  // ---- compute-side byte bases ----
  const int aBase = (hl * 128 + wm * 64 + l31) * 16;   // + s*4096 (+512 fb=1)
  const int bBase = (hl * 256 + wn * 64 + l31) * 16;   // + s*8192 (+512 fo=1)

  f32x16 acc[2][2];
#pragma unroll
  for (int i = 0; i < 2; ++i)
#pragma unroll
    for (int j = 0; j < 2; ++j)
#pragma unroll
      for (int r = 0; r < 16; ++r) acc[i][j][r] = 0.f;

  // ---- A-gen state: 16 i-values/thread + preloaded x chunk ----
  float bb[16], ff[16];
  float4 xh[4];                               // current/next x chunk (16 floats)

  // ================= prologue =================
#pragma unroll
  for (int q = 0; q < 4; ++q) xh[q] = *(const float4*)(xg + q * 4);   // chunk 0
  STAGE(0, 0);
  STAGE(1, 1);
  {
    float f[16];
#pragma unroll
    for (int q = 0; q < 4; ++q) {
      f[q*4+0] = xh[q].x; f[q*4+1] = xh[q].y; f[q*4+2] = xh[q].z; f[q*4+3] = xh[q].w;
    }
    unsigned int w[8];
#pragma unroll
    for (int j = 0; j < 8; ++j) CVTPK(w[j], f[2*j], f[2*j+1]);
    char* pAe = (char*)&Asw[0][0];
    *(u32x4*)(pAe + aoff0) = (u32x4){w[0], w[1], w[2], w[3]};
    *(u32x4*)(pAe + aoff1) = (u32x4){w[4], w[5], w[6], w[7]};
#pragma unroll
    for (int j = 0; j < 16; ++j) {
      float u = fmaf(f[j], 1.375f, 5.5f);
      bb[j] = exp2f(-0.72134752044448170f * u * u);                         // g=0 basis
      ff[j] = exp2f(fmaf(u, 1.44269504088896340f, -0.72134752044448170f)); // exp(u-1/2)
    }
  }
  asm volatile("s_waitcnt vmcnt(4) lgkmcnt(0)" ::: "memory");  // B[0]+A(0) ready
  __builtin_amdgcn_s_barrier();

  // ================= main loop =================
  int cur3 = 0, tm13 = 0, cchunk = 1;
#pragma unroll 1
  for (int t = 0; t < NSTEP; ++t) {
    const char* pA  = (const char*)&Asw[t & 1][0];
    const char* pB  = (const char*)&Bsw[cur3][0];
    char*       pAe = (char*)&Asw[(t + 1) & 1][0];

    // 1. ds_reads for step t (early: longest latency lead)
    short8 av[2][4], bv[2][4];
#pragma unroll
    for (int s = 0; s < 4; ++s) {
      av[0][s] = *(const short8*)(pA + aBase + s * 4096);
      av[1][s] = *(const short8*)(pA + aBase + s * 4096 + 512);
      bv[0][s] = *(const short8*)(pB + bBase + s * 8192);
      bv[1][s] = *(const short8*)(pB + bBase + s * 8192 + 512);
    }

    // 2. stage B(t+2)
    const bool doStage = (t < NSTEP - 2);
    {
      int nring = cur3 + 2; if (nring >= 3) nring -= 3;
      if (doStage) STAGE(t + 2, nring);
    }

    // 3. emit A(t+1): cvtpk + 2 ds_write (VALU-light; recurrence deferred)
    if (t < NSTEP - 1) {
      unsigned int w[8];
      if (tm13 == 12) {                       // next step is slot 0: A = x
        float f[16];
#pragma unroll
        for (int q = 0; q < 4; ++q) {
          f[q*4+0] = xh[q].x; f[q*4+1] = xh[q].y; f[q*4+2] = xh[q].z; f[q*4+3] = xh[q].w;
        }
#pragma unroll
        for (int j = 0; j < 8; ++j) CVTPK(w[j], f[2*j], f[2*j+1]);
      } else {
#pragma unroll
        for (int j = 0; j < 8; ++j) CVTPK(w[j], bb[2*j], bb[2*j+1]);
      }
      *(u32x4*)(pAe + aoff0) = (u32x4){w[0], w[1], w[2], w[3]};
      *(u32x4*)(pAe + aoff1) = (u32x4){w[4], w[5], w[6], w[7]};
    }

    // 4. MFMA cluster (compiler inserts fine-grained lgkm waits for the reads)
    __builtin_amdgcn_s_setprio(1);
#pragma unroll
    for (int s = 0; s < 4; ++s) {
      acc[0][0] = __builtin_amdgcn_mfma_f32_32x32x16_bf16(av[0][s], bv[0][s], acc[0][0], 0, 0, 0);
      acc[0][1] = __builtin_amdgcn_mfma_f32_32x32x16_bf16(av[0][s], bv[1][s], acc[0][1], 0, 0, 0);
      acc[1][0] = __builtin_amdgcn_mfma_f32_32x32x16_bf16(av[1][s], bv[0][s], acc[1][0], 0, 0, 0);
      acc[1][1] = __builtin_amdgcn_mfma_f32_32x32x16_bf16(av[1][s], bv[1][s], acc[1][1], 0, 0, 0);
    }
    __builtin_amdgcn_s_setprio(0);

    // 5. shadow: state advance for emit(t+2) + x chunk preload (fills drain)
    if (t < NSTEP - 2) {
      if (tm13 == 12) {                       // (t+2) is slot 1: re-init from xh
#pragma unroll
        for (int j = 0; j < 16; ++j) {
          float xv = (j < 4 ? (&xh[0].x)[j] : j < 8 ? (&xh[1].x)[j-4]
                     : j < 12 ? (&xh[2].x)[j-8] : (&xh[3].x)[j-12]);
          float u = fmaf(xv, 1.375f, 5.5f);
          bb[j] = exp2f(-0.72134752044448170f * u * u);
          ff[j] = exp2f(fmaf(u, 1.44269504088896340f, -0.72134752044448170f));
        }
      } else if (tm13 != 11) {                // (t+2)%13 != 0: advance recurrence
#pragma unroll
        for (int j = 0; j < 16; ++j) {
          bb[j] *= ff[j];
          ff[j] *= 0.36787944117144233f;      // e^-1
        }
      }
    }
    bool xstep = (tm13 == 2) && (cchunk < 8);
    if (xstep) {                              // preload next x chunk (10 steps early)
      const float* xn = xg + (size_t)cchunk * 64;
#pragma unroll
      for (int q = 0; q < 4; ++q) xh[q] = *(const float4*)(xn + q * 4);
      ++cchunk;
    }

    // 6. counted fence + single barrier
    if (!doStage) {
      asm volatile("s_waitcnt vmcnt(0) lgkmcnt(0)" ::: "memory");
    } else if (xstep) {
      asm volatile("s_waitcnt vmcnt(8) lgkmcnt(0)" ::: "memory");
    } else {
      asm volatile("s_waitcnt vmcnt(4) lgkmcnt(0)" ::: "memory");
    }
    __builtin_amdgcn_s_barrier();

    if (++tm13 == 13) tm13 = 0;
    cur3 = (cur3 == 2) ? 0 : cur3 + 1;
  }

  // ---- epilogue: D col(o) = lane&31, row(b) = (r&3)+8*(r>>2)+4*hl ----
  float bvv[2];
#pragma unroll
  for (int fo = 0; fo < 2; ++fo) bvv[fo] = bias[N0 + wn * 64 + fo * 32 + l31];
  const int rbase = 4 * hl;
#pragma unroll
  for (int fb = 0; fb < 2; ++fb) {
#pragma unroll
    for (int fo = 0; fo < 2; ++fo) {
      const size_t cix = (size_t)(N0 + wn * 64 + fo * 32 + l31);
#pragma unroll
      for (int r = 0; r < 16; ++r) {
        int row = M0 + wm * 64 + fb * 32 + (r & 3) + 8 * (r >> 2) + rbase;
        out[(size_t)row * N_DIM + cix] = acc[fb][fo][r] + bvv[fo];
      }
    }
  }
}

extern "C" void kernel_launch(void* const* d_in, const int* in_sizes, int n_in,
                              void* d_out, int out_size, void* d_ws, size_t ws_size,
                              hipStream_t stream) {
  const float* x      = (const float*)d_in[0];
  const float* coeff  = (const float*)d_in[1];
  const float* base_w = (const float*)d_in[2];
  const float* base_b = (const float*)d_in[3];
  // d_in[4] (centers) is implied by u = x*1.375 + 5.5 (exact)
  unsigned short* Wb2 = (unsigned short*)d_ws;   // needs 6,815,744 B

  prep_w<<<3328, 256, 0, stream>>>(coeff, base_w, Wb2);
  kan_gemm<<<256, 512, 0, stream>>>(x, Wb2, base_b, (float*)d_out);
}